// Round 1
// baseline (298.275 us; speedup 1.0000x reference)
//
#include <hip/hip_runtime.h>

typedef __attribute__((ext_vector_type(8))) short short8;
typedef __attribute__((ext_vector_type(4))) float f32x4;

#define MFMA16(a, b, c) __builtin_amdgcn_mfma_f32_16x16x32_bf16(a, b, c, 0, 0, 0)

// Problem constants
#define BATCH 2
#define SEQ 2048
#define DMODEL 1024
#define NHEADS 16
#define HDIM 64
#define MROWS (BATCH * SEQ)      // 4096
#define N_QKV (3 * DMODEL)       // 3072

static __device__ __forceinline__ unsigned short f2bf(float f) {
  unsigned int u = __float_as_uint(f);
  u = (u + 0x7fff + ((u >> 16) & 1)) >> 16;   // round-to-nearest-even
  return (unsigned short)u;
}

// ---------------------------------------------------------------- cvt fp32->bf16
__global__ void cvt_kernel(const float* __restrict__ in,
                           unsigned short* __restrict__ out, int n4) {
  int i = blockIdx.x * blockDim.x + threadIdx.x;
  if (i >= n4) return;
  f32x4 v = ((const f32x4*)in)[i];
  ushort4 o;
  o.x = f2bf(v[0]); o.y = f2bf(v[1]); o.z = f2bf(v[2]); o.w = f2bf(v[3]);
  ((ushort4*)out)[i] = o;
}

// ---------------------------------------------------------------- mask -> bitmask
// bits[row*64 + w] bit b = (mask[row*2048 + w*32 + b] != 0)
__global__ void mask_to_bits(const int* __restrict__ mask,
                             unsigned int* __restrict__ bits) {
  int i = blockIdx.x * blockDim.x + threadIdx.x;   // 0 .. 2048*64-1
  const int* p = mask + (size_t)i * 32;
  unsigned int v = 0;
#pragma unroll
  for (int b = 0; b < 32; ++b) v |= (p[b] != 0 ? 1u : 0u) << b;
  bits[i] = v;
}

// ---------------------------------------------------------------- NT GEMM, 128x128 tile
// C[M,N] = A[M,K] * B[N,K]^T + bias[N]
// EPI 0: scatter bf16 into q/k/vt buffers (QKV projection)
// EPI 1: fp32 store to Cout (output projection)
template <int EPI>
__global__ __launch_bounds__(256) void gemm_bt(
    const unsigned short* __restrict__ A, const unsigned short* __restrict__ Bm,
    const float* __restrict__ bias, int Kdim, int Ndim,
    unsigned short* __restrict__ qb, unsigned short* __restrict__ kb,
    unsigned short* __restrict__ vtb, float* __restrict__ Cout) {
  __shared__ __align__(16) unsigned short lA[128 * 40];  // stride 40: 2-way bank alias (free)
  __shared__ __align__(16) unsigned short lB[128 * 40];

  int t = threadIdx.x;
  int m0 = blockIdx.y * 128, n0 = blockIdx.x * 128;
  int w = t >> 6, lane = t & 63, quad = lane >> 4, l16 = lane & 15;
  int wm = (w >> 1) * 64, wn = (w & 1) * 64;

  f32x4 acc[4][4];
#pragma unroll
  for (int i = 0; i < 4; ++i)
#pragma unroll
    for (int j = 0; j < 4; ++j) acc[i][j] = (f32x4){0.f, 0.f, 0.f, 0.f};

  int nK = Kdim >> 5;
  for (int kk = 0; kk < nK; ++kk) {
    __syncthreads();
#pragma unroll
    for (int c = 0; c < 2; ++c) {
      int id = t + c * 256;
      int row = id >> 2, c8 = (id & 3) << 3;
      *(uint4*)&lA[row * 40 + c8] =
          *(const uint4*)&A[(size_t)(m0 + row) * Kdim + (kk << 5) + c8];
      *(uint4*)&lB[row * 40 + c8] =
          *(const uint4*)&Bm[(size_t)(n0 + row) * Kdim + (kk << 5) + c8];
    }
    __syncthreads();
    short8 af[4], bfr[4];
#pragma unroll
    for (int i = 0; i < 4; ++i)
      af[i] = *(const short8*)&lA[(wm + i * 16 + l16) * 40 + quad * 8];
#pragma unroll
    for (int j = 0; j < 4; ++j)
      bfr[j] = *(const short8*)&lB[(wn + j * 16 + l16) * 40 + quad * 8];
#pragma unroll
    for (int i = 0; i < 4; ++i)
#pragma unroll
      for (int j = 0; j < 4; ++j) acc[i][j] = MFMA16(af[i], bfr[j], acc[i][j]);
  }

  // epilogue: C/D layout col=lane&15, row=quad*4+reg (m89-verified)
#pragma unroll
  for (int j = 0; j < 4; ++j) {
    int n = n0 + wn + j * 16 + l16;
    float bs = bias[n];
#pragma unroll
    for (int i = 0; i < 4; ++i) {
#pragma unroll
      for (int r = 0; r < 4; ++r) {
        int m = m0 + wm + i * 16 + quad * 4 + r;
        float v = acc[i][j][r] + bs;
        if (EPI == 0) {
          int b = m >> 11, s = m & 2047;
          int h = n / 192, rr = n % 192;
          int bh = (b << 4) + h;
          if (rr < 64)
            qb[((size_t)bh * SEQ + s) * HDIM + rr] = f2bf(v);
          else if (rr < 128)
            kb[((size_t)bh * SEQ + s) * HDIM + (rr - 64)] = f2bf(v);
          else
            vtb[((size_t)bh * HDIM + (rr - 128)) * SEQ + s] = f2bf(v);
        } else {
          Cout[(size_t)m * Ndim + n] = v;
        }
      }
    }
  }
}

// ---------------------------------------------------------------- flash attention
// grid: (16 q-tiles, 32 bh). block 256 = 4 waves; wave handles 32 q-rows.
__global__ __launch_bounds__(256) void attn_kernel(
    const unsigned short* __restrict__ qbuf, const unsigned short* __restrict__ kbuf,
    const unsigned short* __restrict__ vtbuf, const unsigned int* __restrict__ mbits,
    unsigned short* __restrict__ ctx) {
  int qt = blockIdx.x, bh = blockIdx.y;
  int q0 = qt * 128;
  const unsigned short* Q = qbuf + (size_t)bh * SEQ * HDIM;
  const unsigned short* K = kbuf + (size_t)bh * SEQ * HDIM;
  const unsigned short* VT = vtbuf + (size_t)bh * HDIM * SEQ;

  __shared__ __align__(16) unsigned short lQ[128 * 72];
  __shared__ __align__(16) unsigned short lK[64 * 72];
  __shared__ __align__(16) unsigned short lV[64 * 72];   // V^T: [d][key]
  __shared__ __align__(16) unsigned short lP[128 * 72];  // per-wave 32-row slices

  int t = threadIdx.x;
  int w = t >> 6, lane = t & 63, quad = lane >> 4, l16 = lane & 15;

  // stage Q tile [128][64]
#pragma unroll
  for (int c = 0; c < 4; ++c) {
    int id = t + c * 256;
    int row = id >> 3, c8 = (id & 7) << 3;
    *(uint4*)&lQ[row * 72 + c8] = *(const uint4*)&Q[(size_t)(q0 + row) * HDIM + c8];
  }

  f32x4 o[2][4];
#pragma unroll
  for (int mt = 0; mt < 2; ++mt)
#pragma unroll
    for (int j = 0; j < 4; ++j) o[mt][j] = (f32x4){0.f, 0.f, 0.f, 0.f};
  float mi[8], li[8];
#pragma unroll
  for (int i = 0; i < 8; ++i) { mi[i] = -INFINITY; li[i] = 0.f; }

  int qbase = q0 + w * 32;

  for (int k0 = 0; k0 < SEQ; k0 += 64) {
    __syncthreads();
    // stage K [64 keys][64 d] and V^T [64 d][64 keys]
#pragma unroll
    for (int c = 0; c < 2; ++c) {
      int id = t + c * 256;
      int row = id >> 3, c8 = (id & 7) << 3;
      *(uint4*)&lK[row * 72 + c8] = *(const uint4*)&K[(size_t)(k0 + row) * HDIM + c8];
      *(uint4*)&lV[row * 72 + c8] = *(const uint4*)&VT[(size_t)row * SEQ + k0 + c8];
    }
    __syncthreads();

    // S = Q K^T
    f32x4 s[2][4];
    short8 aq[2][2];
#pragma unroll
    for (int mt = 0; mt < 2; ++mt)
#pragma unroll
      for (int kh = 0; kh < 2; ++kh)
        aq[mt][kh] =
            *(const short8*)&lQ[(w * 32 + mt * 16 + l16) * 72 + kh * 32 + quad * 8];
#pragma unroll
    for (int j = 0; j < 4; ++j) {
      short8 b0 = *(const short8*)&lK[(j * 16 + l16) * 72 + quad * 8];
      short8 b1 = *(const short8*)&lK[(j * 16 + l16) * 72 + 32 + quad * 8];
#pragma unroll
      for (int mt = 0; mt < 2; ++mt) {
        f32x4 z = (f32x4){0.f, 0.f, 0.f, 0.f};
        z = MFMA16(aq[mt][0], b0, z);
        z = MFMA16(aq[mt][1], b1, z);
        s[mt][j] = z;
      }
    }

    // mask + scale (bitmask; keys j*16+l16 within 64-key tile)
#pragma unroll
    for (int mt = 0; mt < 2; ++mt)
#pragma unroll
      for (int r = 0; r < 4; ++r) {
        int qrow = qbase + mt * 16 + quad * 4 + r;
        unsigned int w0 = mbits[qrow * 64 + (k0 >> 5)];
        unsigned int w1 = mbits[qrow * 64 + (k0 >> 5) + 1];
        s[mt][0][r] = ((w0 >> l16) & 1) ? s[mt][0][r] * 0.125f : -1e30f;
        s[mt][1][r] = ((w0 >> (16 + l16)) & 1) ? s[mt][1][r] * 0.125f : -1e30f;
        s[mt][2][r] = ((w1 >> l16) & 1) ? s[mt][2][r] * 0.125f : -1e30f;
        s[mt][3][r] = ((w1 >> (16 + l16)) & 1) ? s[mt][3][r] * 0.125f : -1e30f;
      }

    // online softmax per row (16 lanes of quad share a row)
#pragma unroll
    for (int mt = 0; mt < 2; ++mt)
#pragma unroll
      for (int r = 0; r < 4; ++r) {
        int idx = mt * 4 + r;
        float mx = fmaxf(fmaxf(s[mt][0][r], s[mt][1][r]),
                         fmaxf(s[mt][2][r], s[mt][3][r]));
        mx = fmaxf(mx, __shfl_xor(mx, 1));
        mx = fmaxf(mx, __shfl_xor(mx, 2));
        mx = fmaxf(mx, __shfl_xor(mx, 4));
        mx = fmaxf(mx, __shfl_xor(mx, 8));
        float mn = fmaxf(mi[idx], mx);
        float al = __expf(mi[idx] - mn);
        float rs = 0.f;
#pragma unroll
        for (int j = 0; j < 4; ++j) {
          float p = __expf(s[mt][j][r] - mn);
          s[mt][j][r] = p;
          rs += p;
        }
        rs += __shfl_xor(rs, 1);
        rs += __shfl_xor(rs, 2);
        rs += __shfl_xor(rs, 4);
        rs += __shfl_xor(rs, 8);
        li[idx] = li[idx] * al + rs;
        mi[idx] = mn;
#pragma unroll
        for (int j = 0; j < 4; ++j) o[mt][j][r] *= al;
      }

    // P (C-layout) -> LDS -> A-layout (per-wave region, no block barrier needed)
#pragma unroll
    for (int mt = 0; mt < 2; ++mt)
#pragma unroll
      for (int j = 0; j < 4; ++j)
#pragma unroll
        for (int r = 0; r < 4; ++r)
          lP[(w * 32 + mt * 16 + quad * 4 + r) * 72 + j * 16 + l16] =
              f2bf(s[mt][j][r]);

    // O += P V
#pragma unroll
    for (int kh = 0; kh < 2; ++kh) {
      short8 ap0 = *(const short8*)&lP[(w * 32 + l16) * 72 + kh * 32 + quad * 8];
      short8 ap1 = *(const short8*)&lP[(w * 32 + 16 + l16) * 72 + kh * 32 + quad * 8];
#pragma unroll
      for (int jt = 0; jt < 4; ++jt) {
        short8 bv = *(const short8*)&lV[(jt * 16 + l16) * 72 + kh * 32 + quad * 8];
        o[0][jt] = MFMA16(ap0, bv, o[0][jt]);
        o[1][jt] = MFMA16(ap1, bv, o[1][jt]);
      }
    }
  }

  // epilogue: ctx[b*S+s][h*64+d] bf16
  int b = bh >> 4, h = bh & 15;
#pragma unroll
  for (int mt = 0; mt < 2; ++mt)
#pragma unroll
    for (int r = 0; r < 4; ++r) {
      float inv = 1.f / li[mt * 4 + r];
      int srow = qbase + mt * 16 + quad * 4 + r;
      size_t base = ((size_t)(b * SEQ + srow)) * DMODEL + h * HDIM;
#pragma unroll
      for (int jt = 0; jt < 4; ++jt)
        ctx[base + jt * 16 + l16] = f2bf(o[mt][jt][r] * inv);
    }
}

// ---------------------------------------------------------------- launch
extern "C" void kernel_launch(void* const* d_in, const int* in_sizes, int n_in,
                              void* d_out, int out_size, void* d_ws, size_t ws_size,
                              hipStream_t stream) {
  const float* x = (const float*)d_in[0];
  const int* mask = (const int*)d_in[1];
  const float* w_qkv = (const float*)d_in[2];
  const float* b_qkv = (const float*)d_in[3];
  const float* w_o = (const float*)d_in[4];
  const float* b_o = (const float*)d_in[5];
  float* out = (float*)d_out;

  char* ws = (char*)d_ws;
  unsigned short* xb = (unsigned short*)(ws);                       // 8 MB
  unsigned short* wqkvb = (unsigned short*)(ws + (8ull << 20));     // 6 MB
  unsigned short* wob = (unsigned short*)(ws + (14ull << 20));      // 2 MB
  unsigned short* qb = (unsigned short*)(ws + (16ull << 20));       // 8 MB
  unsigned short* kb = (unsigned short*)(ws + (24ull << 20));       // 8 MB
  unsigned short* vtb = (unsigned short*)(ws + (32ull << 20));      // 8 MB
  unsigned short* ctx = (unsigned short*)(ws + (40ull << 20));      // 8 MB
  unsigned int* mbits = (unsigned int*)(ws + (48ull << 20));        // 512 KB

  cvt_kernel<<<4096, 256, 0, stream>>>(x, xb, (MROWS * DMODEL) / 4);
  cvt_kernel<<<3072, 256, 0, stream>>>(w_qkv, wqkvb, (N_QKV * DMODEL) / 4);
  cvt_kernel<<<1024, 256, 0, stream>>>(w_o, wob, (DMODEL * DMODEL) / 4);
  mask_to_bits<<<512, 256, 0, stream>>>(mask, mbits);

  gemm_bt<0><<<dim3(N_QKV / 128, MROWS / 128), 256, 0, stream>>>(
      xb, wqkvb, b_qkv, DMODEL, N_QKV, qb, kb, vtb, nullptr);

  attn_kernel<<<dim3(SEQ / 128, BATCH * NHEADS), 256, 0, stream>>>(
      qb, kb, vtb, mbits, ctx);

  gemm_bt<1><<<dim3(DMODEL / 128, MROWS / 128), 256, 0, stream>>>(
      ctx, wob, b_o, DMODEL, DMODEL, nullptr, nullptr, nullptr, out);
}